// Round 2
// baseline (476.432 us; speedup 1.0000x reference)
//
#include <hip/hip_runtime.h>
#include <cfloat>
#include <cstddef>

// VQ-VAE vector quantizer, MI355X / gfx950.
// z: (32, 64, 32, 32) f32 BCHW; embedding: (1024, 64) f32.
// Outputs concatenated f32: loss[1], z_q(BCHW)[2097152], perplexity[1],
// min_encodings[32768*1024], min_encoding_indices(as float)[32768].
//
// Argmin strategy: emulate the reference's fp32 arithmetic, NOT exact math.
// d_j = fl32( fl32(z2 + e2_j) - 2*dot_j ) at magnitude ~64 quantizes the
// comparison onto the ulp(64)=7.6e-6 grid; ~50/32768 rows have a different
// argmin under this quantization than under exact math. z2/e2 are computed
// in double and rounded once to fp32 (correctly-rounded intermediates);
// 1-ulp z2 differences translate the whole row uniformly -> argmin-safe.
// Grid ties are common -> first-index (lowest j) tie-break matches np.argmin.

#define NROWS      32768        // B*H*W
#define NE         1024
#define EDIM       64
#define RPB        64           // rows per block
#define NBLK       (NROWS / RPB)  // 512

#define OFF_LOSS   ((size_t)0)
#define OFF_ZQ     ((size_t)1)
#define OFF_PERP   ((size_t)2097153)
#define OFF_OH     ((size_t)2097154)
#define OFF_IDX    ((size_t)35651586)

// ws layout (bytes): [0,4096) int hist[1024]; [4096,8192) float e2[1024];
// [8192, 8192+4*NBLK) float partial_loss[512]

__global__ __launch_bounds__(1024) void vq_init(const float* __restrict__ emb,
                                                int* __restrict__ hist,
                                                float* __restrict__ e2) {
    int i = threadIdx.x;  // 0..1023
    hist[i] = 0;
    const float4* e4 = (const float4*)(emb + ((size_t)i << 6));
    double s = 0.0;
#pragma unroll
    for (int k = 0; k < 16; ++k) {
        float4 v = e4[k];
        s += (double)v.x * (double)v.x;
        s += (double)v.y * (double)v.y;
        s += (double)v.z * (double)v.z;
        s += (double)v.w * (double)v.w;
    }
    e2[i] = (float)s;   // correctly-rounded fp32 ||e_j||^2
}

__global__ __launch_bounds__(256) void vq_main(const float* __restrict__ z,
                                               const float* __restrict__ emb,
                                               const float* __restrict__ e2s,
                                               int* __restrict__ hist,
                                               float* __restrict__ partial,
                                               float* __restrict__ out) {
    const int t    = threadIdx.x;
    const int lane = t & 63;
    const int q    = t >> 6;          // wave id = code quarter
    const int r0   = blockIdx.x * RPB;
    const int row  = r0 + lane;       // this lane's z-row
    const int b    = row >> 10;       // batch index (1024 rows per batch)
    const int m    = row & 1023;      // h*32+w
    const size_t zbase = (size_t)b * 65536 + (size_t)m;

    // ---- load this lane's z row (64 ch, stride 1024 floats) into VGPRs ----
    float4 zr[16];
#pragma unroll
    for (int k = 0; k < 16; ++k) {
        float4 v;
        v.x = z[zbase + (size_t)(4 * k + 0) * 1024];
        v.y = z[zbase + (size_t)(4 * k + 1) * 1024];
        v.z = z[zbase + (size_t)(4 * k + 2) * 1024];
        v.w = z[zbase + (size_t)(4 * k + 3) * 1024];
        zr[k] = v;
    }

    // ---- ||z||^2 in double, rounded once to fp32 ----
    double z2d = 0.0;
#pragma unroll
    for (int k = 0; k < 16; ++k) {
        z2d += (double)zr[k].x * (double)zr[k].x;
        z2d += (double)zr[k].y * (double)zr[k].y;
        z2d += (double)zr[k].z * (double)zr[k].z;
        z2d += (double)zr[k].w * (double)zr[k].w;
    }
    const float z2f = (float)z2d;

    // ---- scan this wave's quarter of the codebook ----
    float bestd = FLT_MAX;
    int   bestj = NE;
    const int j0 = q * 256;
    for (int j = j0; j < j0 + 256; ++j) {
        const float4* e4 = (const float4*)(emb + ((size_t)j << 6));
        float d0 = 0.f, d1 = 0.f, d2 = 0.f, d3 = 0.f;
#pragma unroll
        for (int k = 0; k < 16; ++k) {
            float4 ev = e4[k];   // wave-uniform address -> broadcast load
            d0 = fmaf(ev.x, zr[k].x, d0);
            d1 = fmaf(ev.y, zr[k].y, d1);
            d2 = fmaf(ev.z, zr[k].z, d2);
            d3 = fmaf(ev.w, zr[k].w, d3);
        }
        float dot = (d0 + d1) + (d2 + d3);
        // reference fp32 rounding sequence:
        //   t = fl(z2 + e2_j)  [magnitude-64 quantization]
        //   d = fl(t - 2*dot)  [2*dot exact; single rounding at 64]
        float tj = z2f + e2s[j];
        float dj = tj - 2.0f * dot;
        if (dj < bestd || (dj == bestd && j < bestj)) { bestd = dj; bestj = j; }
    }

    // ---- combine 4 per-wave candidates per row; first-index tie-break ----
    __shared__ float s_d[4][64];
    __shared__ int   s_j[4][64];
    __shared__ int   s_idx[64];
    __shared__ float s_l[4];
    s_d[q][lane] = bestd;
    s_j[q][lane] = bestj;
    __syncthreads();
    if (t < 64) {
        float bd = s_d[0][t];
        int   bj = s_j[0][t];
#pragma unroll
        for (int w = 1; w < 4; ++w) {
            float dw = s_d[w][t];
            int   jw = s_j[w][t];
            if (dw < bd || (dw == bd && jw < bj)) { bd = dw; bj = jw; }
        }
        s_idx[t] = bj;
        out[OFF_IDX + (size_t)(r0 + t)] = (float)bj;   // indices as float
        atomicAdd(&hist[bj], 1);
    }
    __syncthreads();

    // ---- z_q (straight-through) + loss partial ----
    // wave q handles channels c = q, q+4, ... for its lane's row
    const int   jj   = s_idx[lane];
    const float* er  = emb + ((size_t)jj << 6);
    float* zq = out + OFF_ZQ + (size_t)b * 65536 + (size_t)m;
    float lsum = 0.f;
#pragma unroll
    for (int c = q; c < EDIM; c += 4) {
        float zc   = z[zbase + (size_t)c * 1024];   // coalesced across lanes
        float ev   = er[c];                         // gather (L1/L2-hot)
        float diff = ev - zc;
        zq[(size_t)c * 1024] = zc + diff;           // mimic zp + (z_q - zp)
        lsum = fmaf(diff, diff, lsum);
    }
    // block loss reduction
#pragma unroll
    for (int off = 32; off >= 1; off >>= 1) lsum += __shfl_down(lsum, off);
    if (lane == 0) s_l[q] = lsum;
    __syncthreads();
    if (t == 0) partial[blockIdx.x] = (s_l[0] + s_l[1]) + (s_l[2] + s_l[3]);

    // ---- one-hot rows: 64 rows x 1024 cols, coalesced float2 stores ----
    // (one-hot region is only 8-byte aligned -> float2, not float4)
    float* oh = out + OFF_OH;
    for (int mm = 0; mm < RPB; ++mm) {
        int    jr   = s_idx[mm];
        float* rowp = oh + (size_t)(r0 + mm) * 1024;
        // cols [2t, 2t+1]
        float2 v0 = make_float2(0.f, 0.f);
        if ((jr >> 1) == t) ((float*)&v0)[jr & 1] = 1.0f;
        ((float2*)rowp)[t] = v0;
        // cols [512+2t, 512+2t+1]
        float2 v1 = make_float2(0.f, 0.f);
        if ((jr >> 1) == t + 256) ((float*)&v1)[jr & 1] = 1.0f;
        ((float2*)rowp)[t + 256] = v1;
    }
}

__global__ __launch_bounds__(1024) void vq_final(const int* __restrict__ hist,
                                                 const float* __restrict__ partial,
                                                 float* __restrict__ out) {
    int t = threadIdx.x;
    // perplexity term
    float p    = (float)hist[t] * (1.0f / 32768.0f);
    float term = p * logf(p + 1e-10f);
    // loss partial
    float lp = (t < NBLK) ? partial[t] : 0.f;
#pragma unroll
    for (int off = 32; off >= 1; off >>= 1) {
        term += __shfl_down(term, off);
        lp   += __shfl_down(lp, off);
    }
    __shared__ float st[16], sl[16];
    int w = t >> 6, ln = t & 63;
    if (ln == 0) { st[w] = term; sl[w] = lp; }
    __syncthreads();
    if (t == 0) {
        float s = 0.f, l = 0.f;
#pragma unroll
        for (int i = 0; i < 16; ++i) { s += st[i]; l += sl[i]; }
        out[OFF_LOSS] = 1.25f * l * (1.0f / 2097152.0f);  // (1+beta)*mean
        out[OFF_PERP] = expf(-s);
    }
}

extern "C" void kernel_launch(void* const* d_in, const int* in_sizes, int n_in,
                              void* d_out, int out_size, void* d_ws, size_t ws_size,
                              hipStream_t stream) {
    const float* z   = (const float*)d_in[0];
    const float* emb = (const float*)d_in[1];
    float* out     = (float*)d_out;
    int*   hist    = (int*)d_ws;
    float* e2      = (float*)((char*)d_ws + 4096);
    float* partial = (float*)((char*)d_ws + 8192);

    vq_init<<<1, 1024, 0, stream>>>(emb, hist, e2);
    vq_main<<<NBLK, 256, 0, stream>>>(z, emb, e2, hist, partial, out);
    vq_final<<<1, 1024, 0, stream>>>(hist, partial, out);
}

// Round 3
// 256.244 us; speedup vs baseline: 1.8593x; 1.8593x over previous
//
#include <hip/hip_runtime.h>
#include <cfloat>
#include <cstddef>

// VQ-VAE vector quantizer, MI355X / gfx950.
// z: (32, 64, 32, 32) f32 BCHW; embedding: (1024, 64) f32.
// Outputs concatenated f32: loss[1], z_q(BCHW)[2097152], perplexity[1],
// min_encodings[32768*1024], min_encoding_indices(as float)[32768].
//
// Argmin: emulate the reference's fp32 rounding (NOT exact math):
//   d_j = fl32( fl32(z2 + e2_j) - 2*dot_j )  at magnitude ~64,
// with z2/e2 double-accumulated and rounded once to fp32, dot via fp32 fma
// chains (error << ulp(64)); first-index tie-break matches np.argmin.
// This passed round 2 bit-exactly (absmax 0.0) — numerics preserved here.

#define NROWS      32768          // B*H*W
#define NE         1024
#define EDIM       64
#define RPB        64             // rows per block
#define NBLK       (NROWS / RPB)  // 512
#define TPB        512            // 8 waves: each scans 128 codes

#define OFF_LOSS   ((size_t)0)
#define OFF_ZQ     ((size_t)1)
#define OFF_PERP   ((size_t)2097153)
#define OFF_OH     ((size_t)2097154)
#define OFF_IDX    ((size_t)35651586)

// ws layout (bytes): [0,4096) int hist[1024]; [4096,6144) float partial[512]

__global__ __launch_bounds__(TPB, 4) void vq_main(const float* __restrict__ z,
                                                  const float* __restrict__ emb,
                                                  int* __restrict__ hist,
                                                  float* __restrict__ partial,
                                                  float* __restrict__ out) {
    const int t    = threadIdx.x;
    const int lane = t & 63;
    const int q    = t >> 6;          // wave id, 0..7
    const int r0   = blockIdx.x * RPB;
    const int row  = r0 + lane;       // this lane's z-row
    const int b    = row >> 10;       // batch (1024 rows per batch image)
    const int m    = row & 1023;      // h*32+w
    const size_t zbase = (size_t)b * 65536 + (size_t)m;

    __shared__ float s_e2[NE];
    __shared__ float s_d[8][64];
    __shared__ int   s_j[8][64];
    __shared__ int   s_idx[64];
    __shared__ float s_l[8];

    // ---- per-block ||e_j||^2 into LDS (double-accumulated, fp32-rounded) --
    for (int j = t; j < NE; j += TPB) {
        const float4* e4 = (const float4*)(emb + ((size_t)j << 6));
        double s = 0.0;
#pragma unroll
        for (int k = 0; k < 16; ++k) {
            float4 v = e4[k];
            s += (double)v.x * (double)v.x;
            s += (double)v.y * (double)v.y;
            s += (double)v.z * (double)v.z;
            s += (double)v.w * (double)v.w;
        }
        s_e2[j] = (float)s;
    }

    // ---- load this lane's z row (64 ch, stride 1024 floats) into VGPRs ----
    float4 zr[16];
#pragma unroll
    for (int k = 0; k < 16; ++k) {
        float4 v;
        v.x = z[zbase + (size_t)(4 * k + 0) * 1024];
        v.y = z[zbase + (size_t)(4 * k + 1) * 1024];
        v.z = z[zbase + (size_t)(4 * k + 2) * 1024];
        v.w = z[zbase + (size_t)(4 * k + 3) * 1024];
        zr[k] = v;
    }

    // ---- ||z||^2 in double, rounded once to fp32 ----
    double z2d = 0.0;
#pragma unroll
    for (int k = 0; k < 16; ++k) {
        z2d += (double)zr[k].x * (double)zr[k].x;
        z2d += (double)zr[k].y * (double)zr[k].y;
        z2d += (double)zr[k].z * (double)zr[k].z;
        z2d += (double)zr[k].w * (double)zr[k].w;
    }
    const float z2f = (float)z2d;

    __syncthreads();   // s_e2 ready

    // ---- scan this wave's 128-code chunk, 2 codes per iteration ----
    // jbase via readfirstlane: provably wave-uniform -> scalar (SGPR) loads
    // for the codebook, which is the natural broadcast path.
    const int jbase = __builtin_amdgcn_readfirstlane(q << 7);
    float bestd = FLT_MAX;
    int   bestj = NE;
    for (int jj = 0; jj < 128; jj += 2) {
        const int ja = jbase + jj;
        const int jb = ja + 1;
        const float4* ea = (const float4*)(emb + ((size_t)ja << 6));
        const float4* eb = (const float4*)(emb + ((size_t)jb << 6));
        float a0 = 0.f, a1 = 0.f, a2 = 0.f, a3 = 0.f;
        float b0 = 0.f, b1 = 0.f, b2 = 0.f, b3 = 0.f;
#pragma unroll
        for (int k = 0; k < 16; ++k) {
            float4 av = ea[k];
            float4 bv = eb[k];
            a0 = fmaf(av.x, zr[k].x, a0);
            a1 = fmaf(av.y, zr[k].y, a1);
            a2 = fmaf(av.z, zr[k].z, a2);
            a3 = fmaf(av.w, zr[k].w, a3);
            b0 = fmaf(bv.x, zr[k].x, b0);
            b1 = fmaf(bv.y, zr[k].y, b1);
            b2 = fmaf(bv.z, zr[k].z, b2);
            b3 = fmaf(bv.w, zr[k].w, b3);
        }
        float dota = (a0 + a1) + (a2 + a3);
        float dotb = (b0 + b1) + (b2 + b3);
        // reference fp32 rounding sequence (two roundings at magnitude ~64)
        float da = (z2f + s_e2[ja]) - 2.0f * dota;
        float db = (z2f + s_e2[jb]) - 2.0f * dotb;
        if (da < bestd || (da == bestd && ja < bestj)) { bestd = da; bestj = ja; }
        if (db < bestd || (db == bestd && jb < bestj)) { bestd = db; bestj = jb; }
    }

    // ---- combine 8 per-wave candidates per row; first-index tie-break ----
    s_d[q][lane] = bestd;
    s_j[q][lane] = bestj;
    __syncthreads();
    if (t < 64) {
        float bd = s_d[0][t];
        int   bj = s_j[0][t];
#pragma unroll
        for (int w = 1; w < 8; ++w) {   // ascending w = ascending code chunks
            float dw = s_d[w][t];
            int   jw = s_j[w][t];
            if (dw < bd || (dw == bd && jw < bj)) { bd = dw; bj = jw; }
        }
        s_idx[t] = bj;
        out[OFF_IDX + (size_t)(r0 + t)] = (float)bj;   // indices as float
        atomicAdd(&hist[bj], 1);
    }
    __syncthreads();

    // ---- z_q (straight-through) + loss partial ----
    // wave q handles channels c = q, q+8, ... for its lane's row
    const int    jjx = s_idx[lane];
    const float* er  = emb + ((size_t)jjx << 6);
    float* zq = out + OFF_ZQ + (size_t)b * 65536 + (size_t)m;
    float lsum = 0.f;
#pragma unroll
    for (int c = q; c < EDIM; c += 8) {
        float zc   = z[zbase + (size_t)c * 1024];   // coalesced across lanes
        float ev   = er[c];                         // gather (L2-hot)
        float diff = ev - zc;
        zq[(size_t)c * 1024] = zc + diff;           // mimic zp + (z_q - zp)
        lsum = fmaf(diff, diff, lsum);
    }
#pragma unroll
    for (int off = 32; off >= 1; off >>= 1) lsum += __shfl_down(lsum, off);
    if (lane == 0) s_l[q] = lsum;
    __syncthreads();
    if (t == 0) {
        float l = 0.f;
#pragma unroll
        for (int w = 0; w < 8; ++w) l += s_l[w];
        partial[blockIdx.x] = l;
    }

    // ---- one-hot rows: 64 rows x 1024 cols, coalesced float2 stores ----
    // (one-hot region is 8-byte aligned -> float2)
    float* oh = out + OFF_OH;
    for (int mm = 0; mm < RPB; ++mm) {
        int    jr   = s_idx[mm];
        float* rowp = oh + (size_t)(r0 + mm) * 1024;
        float2 v0 = make_float2(0.f, 0.f);
        if ((jr >> 1) == t) ((float*)&v0)[jr & 1] = 1.0f;
        ((float2*)rowp)[t] = v0;    // cols [2t, 2t+1], t in [0,512)
    }
}

__global__ __launch_bounds__(1024) void vq_final(const int* __restrict__ hist,
                                                 const float* __restrict__ partial,
                                                 float* __restrict__ out) {
    int t = threadIdx.x;
    float p    = (float)hist[t] * (1.0f / 32768.0f);
    float term = p * logf(p + 1e-10f);
    float lp   = (t < NBLK) ? partial[t] : 0.f;
#pragma unroll
    for (int off = 32; off >= 1; off >>= 1) {
        term += __shfl_down(term, off);
        lp   += __shfl_down(lp, off);
    }
    __shared__ float st[16], sl[16];
    int w = t >> 6, ln = t & 63;
    if (ln == 0) { st[w] = term; sl[w] = lp; }
    __syncthreads();
    if (t == 0) {
        float s = 0.f, l = 0.f;
#pragma unroll
        for (int i = 0; i < 16; ++i) { s += st[i]; l += sl[i]; }
        out[OFF_LOSS] = 1.25f * l * (1.0f / 2097152.0f);  // (1+beta)*mean
        out[OFF_PERP] = expf(-s);
    }
}

extern "C" void kernel_launch(void* const* d_in, const int* in_sizes, int n_in,
                              void* d_out, int out_size, void* d_ws, size_t ws_size,
                              hipStream_t stream) {
    const float* z   = (const float*)d_in[0];
    const float* emb = (const float*)d_in[1];
    float* out     = (float*)d_out;
    int*   hist    = (int*)d_ws;
    float* partial = (float*)((char*)d_ws + 4096);

    hipMemsetAsync(hist, 0, 4096, stream);
    vq_main<<<NBLK, TPB, 0, stream>>>(z, emb, hist, partial, out);
    vq_final<<<1, 1024, 0, stream>>>(hist, partial, out);
}